// Round 1
// baseline (321.527 us; speedup 1.0000x reference)
//
#include <hip/hip_runtime.h>

// ---------------------------------------------------------------------------
// LabelSimilarity: match[b,l] = max(-1, max_{s,v} cos(embed[s,b,:], label[l,v,:]))
// S=256 B=128 D=768 ; L=200 V=8 ; out [128,200] fp32
//
// Strategy: pre-normalize rows to bf16 (GEMM output == cosine), then an
// m97-style 128x128x32 bf16 MFMA GEMM (M=s*128+b, N=l*8+v padded to 1664),
// fused max-over-v (lane shuffle) + max-over-s (atomicMax on monotonic uint
// keys). Tiny init/finalize kernels handle the key transform.
// ---------------------------------------------------------------------------

typedef __bf16 bf16x8 __attribute__((ext_vector_type(8)));
typedef float  f32x4  __attribute__((ext_vector_type(4)));

#define GLD16(gp, lp) __builtin_amdgcn_global_load_lds(                        \
    (__attribute__((address_space(1))) void*)(gp),                             \
    (__attribute__((address_space(3))) void*)(lp), 16, 0, 0)

__device__ __forceinline__ unsigned short f32_to_bf16_rne(float x) {
  unsigned u = __float_as_uint(x);
  u += 0x7fffu + ((u >> 16) & 1u);
  return (unsigned short)(u >> 16);
}

// One wave per row: L2-normalize a 768-elem fp32 row -> bf16. Rows >= nsrc are
// zero pad rows (for N padding 1600->1664).
__global__ void __launch_bounds__(256) normalize_rows(
    const float* __restrict__ src, unsigned short* __restrict__ dst,
    int nsrc, int ndst) {
  int row  = blockIdx.x * 4 + (threadIdx.x >> 6);
  int lane = threadIdx.x & 63;
  if (row >= ndst) return;
  ushort4* drow = (ushort4*)(dst + (size_t)row * 768);
  if (row >= nsrc) {
    ushort4 z; z.x = z.y = z.z = z.w = 0;
#pragma unroll
    for (int t = 0; t < 3; ++t) drow[lane + 64 * t] = z;
    return;
  }
  const float4* srow = (const float4*)(src + (size_t)row * 768);
  float4 v[3];
  float ss = 0.f;
#pragma unroll
  for (int t = 0; t < 3; ++t) {
    v[t] = srow[lane + 64 * t];
    ss += v[t].x * v[t].x + v[t].y * v[t].y + v[t].z * v[t].z + v[t].w * v[t].w;
  }
#pragma unroll
  for (int off = 1; off < 64; off <<= 1) ss += __shfl_xor(ss, off);
  float rinv = rsqrtf(fmaxf(ss, 1e-12f));
#pragma unroll
  for (int t = 0; t < 3; ++t) {
    ushort4 h;
    h.x = f32_to_bf16_rne(v[t].x * rinv);
    h.y = f32_to_bf16_rne(v[t].y * rinv);
    h.z = f32_to_bf16_rne(v[t].z * rinv);
    h.w = f32_to_bf16_rne(v[t].w * rinv);
    drow[lane + 64 * t] = h;
  }
}

// key(-1.0f): u=0xBF800000 (negative) -> ~u = 0x407FFFFF
__global__ void __launch_bounds__(256) init_out_keys(unsigned* outU, int n) {
  int i = blockIdx.x * 256 + threadIdx.x;
  if (i < n) outU[i] = 0x407FFFFFu;
}

// GEMM + fused max epilogue. Block = (n-tile bx in [0,13), s = by in [0,256)).
// A-tile rows = s*128 + b (all b), so M-max == s-max (cross-block atomics).
__global__ void __launch_bounds__(256) gemm_max_kernel(
    const unsigned short* __restrict__ Ap,   // [32768][768] bf16 (normalized)
    const unsigned short* __restrict__ Bp,   // [1664][768]  bf16 (normalized)
    unsigned* __restrict__ outU) {           // [128*200] monotonic keys
  __shared__ unsigned short As[4096];  // [128][32] bf16
  __shared__ unsigned short Bs[4096];  // [128][32] bf16

  const int t    = threadIdx.x;
  const int lane = t & 63;
  const int w    = t >> 6;             // wave 0..3
  const int s    = blockIdx.y;
  const int n0   = blockIdx.x * 128;

  // --- global_load_lds staging addresses (16B/lane, wave-uniform LDS base) ---
  const int q0 = t * 16;               // byte index within 8KB tile, chunk 0
  const int q1 = q0 + 4096;            // chunk 1
  const char* gA = (const char*)(Ap + (size_t)(s * 128) * 768);
  const char* gB = (const char*)(Bp + (size_t)n0 * 768);
  const char* ga0 = gA + (q0 >> 6) * 1536 + (q0 & 63);
  const char* ga1 = gA + (q1 >> 6) * 1536 + (q1 & 63);
  const char* gb0 = gB + (q0 >> 6) * 1536 + (q0 & 63);
  const char* gb1 = gB + (q1 >> 6) * 1536 + (q1 & 63);
  char* lA0 = (char*)As + w * 1024;
  char* lA1 = (char*)As + 4096 + w * 1024;
  char* lB0 = (char*)Bs + w * 1024;
  char* lB1 = (char*)Bs + 4096 + w * 1024;

  // --- wave tile: 2x2 waves, each 64x64 = 4x4 MFMA tiles of 16x16 ---
  const int wm  = (w >> 1) * 64;
  const int wn  = (w & 1) * 64;
  const int r16 = lane & 15;
  const int kq  = (lane >> 4) * 8;     // A/B operand: k = (lane>>4)*8 + j
  const int aoff = (wm + r16) * 32 + kq;
  const int boff = (wn + r16) * 32 + kq;

  f32x4 acc[4][4];
#pragma unroll
  for (int i = 0; i < 4; ++i)
#pragma unroll
    for (int j = 0; j < 4; ++j)
      acc[i][j] = (f32x4){0.f, 0.f, 0.f, 0.f};

  for (int kk = 0; kk < 24; ++kk) {    // K = 768 = 24 * 32
    GLD16(ga0, lA0); GLD16(ga1, lA1);
    GLD16(gb0, lB0); GLD16(gb1, lB1);
    ga0 += 64; ga1 += 64; gb0 += 64; gb1 += 64;
    __syncthreads();                   // drains vmcnt -> LDS tiles ready
    bf16x8 af[4], bfr[4];
#pragma unroll
    for (int i = 0; i < 4; ++i) af[i]  = *(const bf16x8*)&As[aoff + i * 512];
#pragma unroll
    for (int j = 0; j < 4; ++j) bfr[j] = *(const bf16x8*)&Bs[boff + j * 512];
#pragma unroll
    for (int i = 0; i < 4; ++i)
#pragma unroll
      for (int j = 0; j < 4; ++j)
        acc[i][j] = __builtin_amdgcn_mfma_f32_16x16x32_bf16(
            af[i], bfr[j], acc[i][j], 0, 0, 0);
    __syncthreads();                   // protect LDS before next stage
  }

  // --- epilogue: acc is cos. C/D layout: col=lane&15, row=(lane>>4)*4+r ---
  // max over v = max over col groups of 8 -> shuffle-xor 1,2,4.
  float* red = (float*)As;             // reuse LDS: [128 b][16 l] floats
  const int rowg   = lane >> 4;        // 0..3
  const int lbit   = (lane >> 3) & 1;  // which l within the 16-wide tile
  const bool writer = (lane & 7) == 0;
#pragma unroll
  for (int i = 0; i < 4; ++i) {
#pragma unroll
    for (int j = 0; j < 4; ++j) {
#pragma unroll
      for (int r = 0; r < 4; ++r) {
        float vv = acc[i][j][r];
        vv = fmaxf(vv, __shfl_xor(vv, 1));
        vv = fmaxf(vv, __shfl_xor(vv, 2));
        vv = fmaxf(vv, __shfl_xor(vv, 4));
        if (writer) {
          int b  = wm + i * 16 + rowg * 4 + r;
          int ll = (wn >> 3) + j * 2 + lbit;
          red[b * 16 + ll] = vv;
        }
      }
    }
  }
  __syncthreads();
  // 2048 values -> atomics spread across all 256 threads (8 each)
  const int lbase = n0 >> 3;
  for (int e = t; e < 2048; e += 256) {
    int b  = e >> 4;
    int lg = lbase + (e & 15);
    if (lg < 200) {
      unsigned u   = __float_as_uint(red[e]);
      unsigned key = (u & 0x80000000u) ? ~u : (u | 0x80000000u);
      atomicMax(&outU[b * 200 + lg], key);
    }
  }
}

__global__ void __launch_bounds__(256) finalize_out(
    const unsigned* __restrict__ outU, float* __restrict__ out, int n) {
  int i = blockIdx.x * 256 + threadIdx.x;
  if (i < n) {
    unsigned key = outU[i];
    unsigned u = (key & 0x80000000u) ? (key & 0x7FFFFFFFu) : ~key;
    out[i] = fmaxf(__uint_as_float(u), -1.0f);  // init key was -1.0 already
  }
}

// Brute-force fp32 fallback (only if ws_size is too small): one block per (b,l).
__global__ void __launch_bounds__(256) fallback_kernel(
    const float* __restrict__ embed, const float* __restrict__ label,
    float* __restrict__ out) {
  int b = blockIdx.x, l = blockIdx.y, t = threadIdx.x;
  float m = -1.0f;
  for (int p = t; p < 2048; p += 256) {
    int s = p >> 3, v = p & 7;
    const float* e = embed + (size_t)(s * 128 + b) * 768;
    const float* q = label + (size_t)(l * 8 + v) * 768;
    float dot = 0.f, ne = 0.f, nl = 0.f;
    for (int d = 0; d < 768; ++d) {
      float x = e[d], y = q[d];
      dot += x * y; ne += x * x; nl += y * y;
    }
    m = fmaxf(m, dot / fmaxf(sqrtf(ne) * sqrtf(nl), 1e-8f));
  }
  for (int off = 1; off < 64; off <<= 1) m = fmaxf(m, __shfl_xor(m, off));
  __shared__ float wmax[4];
  if ((t & 63) == 0) wmax[t >> 6] = m;
  __syncthreads();
  if (t == 0)
    out[b * 200 + l] = fmaxf(fmaxf(wmax[0], wmax[1]), fmaxf(wmax[2], wmax[3]));
}

extern "C" void kernel_launch(void* const* d_in, const int* in_sizes, int n_in,
                              void* d_out, int out_size, void* d_ws, size_t ws_size,
                              hipStream_t stream) {
  const float* embed = (const float*)d_in[0];   // [256,128,768]
  const float* label = (const float*)d_in[1];   // [200,8,768]
  float* out = (float*)d_out;                   // [128,200]

  const size_t szA = (size_t)32768 * 768 * 2;   // 50,331,648
  const size_t szB = (size_t)1664 * 768 * 2;    //  2,555,904
  const size_t szU = (size_t)25600 * 4;         //    102,400

  if (ws_size < szA + szB + szU) {
    dim3 g(128, 200);
    fallback_kernel<<<g, 256, 0, stream>>>(embed, label, out);
    return;
  }

  unsigned short* Ap  = (unsigned short*)d_ws;
  unsigned short* Bp  = (unsigned short*)((char*)d_ws + szA);
  unsigned*       oU  = (unsigned*)((char*)d_ws + szA + szB);

  normalize_rows<<<32768 / 4, 256, 0, stream>>>(embed, Ap, 32768, 32768);
  normalize_rows<<<1664 / 4, 256, 0, stream>>>(label, Bp, 1600, 1664);
  init_out_keys<<<100, 256, 0, stream>>>(oU, 25600);
  dim3 g(13, 256);  // 13 n-tiles x 256 s  = 3328 blocks (~13/CU)
  gemm_max_kernel<<<g, 256, 0, stream>>>(Ap, Bp, oU);
  finalize_out<<<100, 256, 0, stream>>>(oU, out, 25600);
}